// Round 9
// baseline (192.173 us; speedup 1.0000x reference)
//
#include <hip/hip_runtime.h>

#define BATCH 8
#define SEQ   1024
#define DIM   768
#define NH    12
#define HD    64
#define NTOK  (BATCH * SEQ)   /* 8192 */
#define QKVN  (3 * DIM)       /* 2304 */
#define QSCALE (0.125f * 1.44269504f)   /* head-dim scale folded with log2e */

typedef short bf8   __attribute__((ext_vector_type(8)));  // 8 bf16 bit patterns
typedef short bf4   __attribute__((ext_vector_type(4)));
typedef float f32x4 __attribute__((ext_vector_type(4)));
typedef int   i32x2 __attribute__((ext_vector_type(2)));
typedef int   i32x4 __attribute__((ext_vector_type(4)));

static __device__ __forceinline__ short f2bf(float f) {
    unsigned u = __float_as_uint(f);
    u += 0x7fffu + ((u >> 16) & 1u);
    return (short)(u >> 16);
}

// RNE-pack two f32 into one VGPR of 2 bf16 (low = a, high = b)
static __device__ __forceinline__ int pack_bf16(float a, float b) {
    unsigned ua = __float_as_uint(a); ua += 0x7fffu + ((ua >> 16) & 1u);
    unsigned ub = __float_as_uint(b); ub += 0x7fffu + ((ub >> 16) & 1u);
    return (int)((ua >> 16) | (ub & 0xffff0000u));
}

static __device__ __forceinline__ float fast_exp2(float x) {
#if __has_builtin(__builtin_amdgcn_exp2f)
    return __builtin_amdgcn_exp2f(x);
#else
    return exp2f(x);
#endif
}

// async global->LDS, 16B per lane, dest = wave-uniform base + lane*16
static __device__ __forceinline__ void gload_lds16(const short* g, short* l) {
    __builtin_amdgcn_global_load_lds(
        (const __attribute__((address_space(1))) void*)g,
        (__attribute__((address_space(3))) void*)l, 16, 0, 0);
}

// ---------------------------------------------------------------------------
// Merged prep: one dispatch does x fp32->bf16 (blocks [0,6144)), w_qkv
// transpose+cast (blocks [6144,7872) as 72x24 of 32x32 tiles), w_proj
// transpose+cast (blocks [7872,8448) as 24x24). Removes two launch gaps.
__global__ __launch_bounds__(256) void prep_k(
        const float* __restrict__ x, short* __restrict__ xb,
        const float* __restrict__ wq, short* __restrict__ wqT,
        const float* __restrict__ wp, short* __restrict__ wpT) {
    const int id = blockIdx.x;
    if (id < 6144) {
        int i = id * 256 + threadIdx.x;
        f32x4 v = ((const f32x4*)x)[i];
        bf4 o;
        o[0] = f2bf(v[0]); o[1] = f2bf(v[1]); o[2] = f2bf(v[2]); o[3] = f2bf(v[3]);
        ((bf4*)xb)[i] = o;
        return;
    }
    __shared__ short t[32][33];
    const float* in; short* out; int R, C, bx, by;
    if (id < 7872) {
        int k = id - 6144; bx = k % (QKVN / 32); by = k / (QKVN / 32);
        in = wq; out = wqT; R = DIM; C = QKVN;
    } else {
        int k = id - 7872; bx = k % (DIM / 32); by = k / (DIM / 32);
        in = wp; out = wpT; R = DIM; C = DIM;
    }
    const int tx = threadIdx.x & 31;
    const int ty = threadIdx.x >> 5;
    const int c0 = bx * 32;
    const int r0 = by * 32;
    #pragma unroll
    for (int i = 0; i < 32; i += 8)
        t[ty + i][tx] = f2bf(in[(size_t)(r0 + ty + i) * C + c0 + tx]);
    __syncthreads();
    #pragma unroll
    for (int i = 0; i < 32; i += 8)
        out[(size_t)(c0 + ty + i) * R + r0 + tx] = t[tx][ty + i];
}

// ---------------------------------------------------------------------------
// GEMM core v2 (R8, verified): 128x128 tile, 4 waves, BK=64, global_load_lds
// width=16, XOR slot swizzle, explicit LDS double buffer, 1 barrier/iter.
static __device__ __forceinline__ void gemm_core_128(
        const short* __restrict__ A, const short* __restrict__ WT,
        int m0, int n0, int tid, short* aL, short* bL, f32x4 acc[4][4]) {
    const int lane = tid & 63;
    const int wid  = tid >> 6;
    const int ln   = lane & 15;
    const int quad = lane >> 4;
    const int wm = (wid >> 1) * 64;
    const int wn = (wid & 1) * 64;

    int rowx[4], colx[4];
    #pragma unroll
    for (int cc = 0; cc < 4; cc++) {
        int cf = (wid * 4 + cc) * 64 + lane;
        int r = cf >> 3;
        rowx[cc] = r;
        colx[cc] = (cf & 7) ^ (r & 7);
    }

    #pragma unroll
    for (int cc = 0; cc < 4; cc++) {
        const int dst = (wid * 4 + cc) * 512;
        gload_lds16(A  + (size_t)(m0 + rowx[cc]) * DIM + colx[cc] * 8, aL + dst);
        gload_lds16(WT + (size_t)(n0 + rowx[cc]) * DIM + colx[cc] * 8, bL + dst);
    }

    for (int it = 0; it < DIM / 64; it++) {
        const int cur = it & 1;
        __syncthreads();
        if (it + 1 < DIM / 64) {
            const int nb = (cur ^ 1) * 8192;
            const int kt = (it + 1) * 64;
            #pragma unroll
            for (int cc = 0; cc < 4; cc++) {
                const int dst = nb + (wid * 4 + cc) * 512;
                gload_lds16(A  + (size_t)(m0 + rowx[cc]) * DIM + kt + colx[cc] * 8, aL + dst);
                gload_lds16(WT + (size_t)(n0 + rowx[cc]) * DIM + kt + colx[cc] * 8, bL + dst);
            }
        }
        const int cb = cur * 8192;
        #pragma unroll
        for (int kc = 0; kc < 2; kc++) {
            const int sw = ((kc * 4 + quad) ^ (ln & 7)) * 8;
            bf8 af[4], bw[4];
            #pragma unroll
            for (int mi = 0; mi < 4; mi++)
                af[mi] = *(const bf8*)&aL[cb + (wm + mi * 16 + ln) * 64 + sw];
            #pragma unroll
            for (int ni = 0; ni < 4; ni++)
                bw[ni] = *(const bf8*)&bL[cb + (wn + ni * 16 + ln) * 64 + sw];
            #pragma unroll
            for (int mi = 0; mi < 4; mi++)
                #pragma unroll
                for (int ni = 0; ni < 4; ni++)
                    acc[mi][ni] = __builtin_amdgcn_mfma_f32_16x16x32_bf16(
                            af[mi], bw[ni], acc[mi][ni], 0, 0, 0);
        }
    }
}

// XCD-aware remap: XCD = id&7 gets 8 consecutive m-tiles over all n-tiles.
static __device__ __forceinline__ void xcd_map(int id, int NX, int& xt, int& yt) {
    int r = id % (NX * 8);
    int g = id / (NX * 8);
    xt = r >> 3;
    yt = ((r & 7) << 3) + g;
}

// ---------------------------------------------------------------------------
// GEMM1: qkv = xb @ w_qkv; scatter Q (pre-scaled), K -> [B,H,N,D], V -> V^T
__global__ __launch_bounds__(256) void gemm_qkv_k(
        const short* __restrict__ X, const short* __restrict__ WT,
        short* __restrict__ Qb, short* __restrict__ Kb, short* __restrict__ VT) {
    __shared__ short aL[2 * 128 * 64];
    __shared__ short bL[2 * 128 * 64];
    const int tid  = threadIdx.x;
    const int lane = tid & 63;
    const int wid  = tid >> 6;
    const int ln   = lane & 15;
    const int quad = lane >> 4;
    int xt, yt;
    xcd_map(blockIdx.x, QKVN / 128, xt, yt);
    const int m0 = yt * 128;
    const int n0 = xt * 128;
    const int wm = (wid >> 1) * 64;
    const int wn = (wid & 1) * 64;

    const f32x4 vzero = {0.f, 0.f, 0.f, 0.f};
    f32x4 acc[4][4];
    #pragma unroll
    for (int i = 0; i < 4; i++)
        #pragma unroll
        for (int j = 0; j < 4; j++) acc[i][j] = vzero;

    gemm_core_128(X, WT, m0, n0, tid, aL, bL, acc);

    const int b = m0 / SEQ;
    const int mt = m0 - b * SEQ;
    #pragma unroll
    for (int ni = 0; ni < 4; ni++) {
        const int nb = n0 + wn + ni * 16;
        const int three = nb / DIM;
        const int rem = nb - three * DIM;
        const int h = rem >> 6;
        const int d = (rem & 63) + ln;
        const size_t bh = (size_t)(b * NH + h);
        if (three < 2) {
            short* dst = (three == 0 ? Qb : Kb) + bh * SEQ * HD;
            const float scl = (three == 0) ? QSCALE : 1.0f;
            #pragma unroll
            for (int mi = 0; mi < 4; mi++) {
                #pragma unroll
                for (int r = 0; r < 4; r++) {
                    int tok = mt + wm + mi * 16 + quad * 4 + r;
                    dst[(size_t)tok * HD + d] = f2bf(acc[mi][ni][r] * scl);
                }
            }
        } else {
            short* dst = VT + bh * HD * SEQ + (size_t)d * SEQ;
            #pragma unroll
            for (int mi = 0; mi < 4; mi++) {
                int tok0 = mt + wm + mi * 16 + quad * 4;
                bf4 v;
                v[0] = f2bf(acc[mi][ni][0]); v[1] = f2bf(acc[mi][ni][1]);
                v[2] = f2bf(acc[mi][ni][2]); v[3] = f2bf(acc[mi][ni][3]);
                *(bf4*)&dst[tok0] = v;
            }
        }
    }
}

// ---------------------------------------------------------------------------
// Flash attention v7: R7's verified compute + DOUBLE-BUFFERED K/V staging
// (one barrier per iter, stage tile k+1 into the idle buffer during tile k's
// compute — same pattern that took the GEMM 69->55). LDS 32 KB, 3 blocks/CU.
__global__ __launch_bounds__(256, 3) void attn_k(
        const short* __restrict__ Qb, const short* __restrict__ Kb,
        const short* __restrict__ VT, short* __restrict__ Ob) {
    __shared__ short kL[2 * 64 * 64];      // [buf][key][d] 8KB each, slot-swizzled
    __shared__ short vL[2 * 64 * 64];      // [buf][d][key]
    const int tid  = threadIdx.x;
    const int lane = tid & 63;
    const int wid  = tid >> 6;
    const int ln   = lane & 15;
    const int quad = lane >> 4;
    const int bh = blockIdx.x;             // XCD-local: all qt of this bh on XCD bh%8
    const int qt = blockIdx.y;             // 0..7
    const size_t base = (size_t)bh * SEQ * HD;
    const short* qg = Qb + base;
    const short* kg = Kb + base;
    const short* vg = VT + base;           // V^T: [d][tok]
    const int q0 = qt * 128 + wid * 32;

    int srow[2], scol[2];
    #pragma unroll
    for (int cc = 0; cc < 2; cc++) {
        int f = (wid * 2 + cc) * 64 + lane;
        int r = f >> 3;
        srow[cc] = r;
        scol[cc] = (f & 7) ^ (r & 7);
    }

    // Q as B-operand (n=query=ln, k=d=quad*8+j)
    bf8 bq[2][2];
    #pragma unroll
    for (int qf = 0; qf < 2; qf++)
        #pragma unroll
        for (int kc = 0; kc < 2; kc++)
            bq[qf][kc] = *(const bf8*)&qg[(size_t)(q0 + qf * 16 + ln) * HD + kc * 32 + quad * 8];

    const f32x4 vzero = {0.f, 0.f, 0.f, 0.f};
    f32x4 o[2][4];
    #pragma unroll
    for (int qf = 0; qf < 2; qf++)
        #pragma unroll
        for (int c = 0; c < 4; c++) o[qf][c] = vzero;
    float l_lane[2] = {0.f, 0.f};

    // prologue: stage tile 0 into buffer 0
    #pragma unroll
    for (int cc = 0; cc < 2; cc++) {
        const int dst = (wid * 2 + cc) * 512;
        gload_lds16(kg + (size_t)srow[cc] * HD + scol[cc] * 8, kL + dst);
        gload_lds16(vg + (size_t)srow[cc] * SEQ + scol[cc] * 8, vL + dst);
    }

    for (int it = 0; it < SEQ / 64; it++) {
        const int cur = it & 1;
        // barrier: drains vmcnt (buf[cur] ready) + all waves done with buf[cur^1]
        __syncthreads();
        if (it + 1 < SEQ / 64) {
            const int nb = (cur ^ 1) * 4096;
            const int ktn = (it + 1) * 64;
            #pragma unroll
            for (int cc = 0; cc < 2; cc++) {
                const int dst = nb + (wid * 2 + cc) * 512;
                gload_lds16(kg + (size_t)(ktn + srow[cc]) * HD + scol[cc] * 8, kL + dst);
                gload_lds16(vg + (size_t)srow[cc] * SEQ + ktn + scol[cc] * 8, vL + dst);
            }
        }
        const int cb = cur * 4096;

        bf8 ak[4][2];
        #pragma unroll
        for (int ng = 0; ng < 4; ng++)
            #pragma unroll
            for (int kc = 0; kc < 2; kc++)
                ak[ng][kc] = *(const bf8*)&kL[cb + (ng * 16 + ln) * 64 + ((kc * 4 + quad) ^ (ln & 7)) * 8];
        bf8 bv[2][4];
        #pragma unroll
        for (int kch = 0; kch < 2; kch++)
            #pragma unroll
            for (int c = 0; c < 4; c++)
                bv[kch][c] = *(const bf8*)&vL[cb + (c * 16 + ln) * 64 + ((kch * 4 + quad) ^ (ln & 7)) * 8];

        #pragma unroll
        for (int qf = 0; qf < 2; qf++) {
            #pragma unroll
            for (int kch = 0; kch < 2; kch++) {
                f32x4 s0 = __builtin_amdgcn_mfma_f32_16x16x32_bf16(ak[2 * kch][0], bq[qf][0], vzero, 0, 0, 0);
                s0 = __builtin_amdgcn_mfma_f32_16x16x32_bf16(ak[2 * kch][1], bq[qf][1], s0, 0, 0, 0);
                f32x4 s1 = __builtin_amdgcn_mfma_f32_16x16x32_bf16(ak[2 * kch + 1][0], bq[qf][0], vzero, 0, 0, 0);
                s1 = __builtin_amdgcn_mfma_f32_16x16x32_bf16(ak[2 * kch + 1][1], bq[qf][1], s1, 0, 0, 0);

                float e0[4], e1[4];
                #pragma unroll
                for (int r = 0; r < 4; r++) {
                    e0[r] = fast_exp2(s0[r]);
                    e1[r] = fast_exp2(s1[r]);
                    l_lane[qf] += e0[r] + e1[r];
                }
                int P0a = pack_bf16(e0[0], e0[1]);
                int P1a = pack_bf16(e0[2], e0[3]);
                int P0b = pack_bf16(e1[0], e1[1]);
                int P1b = pack_bf16(e1[2], e1[3]);
                i32x2 t0 = __builtin_amdgcn_permlane32_swap(P0a, P0b, false, false);
                i32x2 u0 = __builtin_amdgcn_permlane16_swap(t0[0], t0[1], false, false);
                i32x2 t1 = __builtin_amdgcn_permlane32_swap(P1a, P1b, false, false);
                i32x2 u1 = __builtin_amdgcn_permlane16_swap(t1[0], t1[1], false, false);
                i32x4 ai;
                ai[0] = u0[0]; ai[1] = u1[0]; ai[2] = u0[1]; ai[3] = u1[1];
                bf8 ap = __builtin_bit_cast(bf8, ai);

                #pragma unroll
                for (int c = 0; c < 4; c++)
                    o[qf][c] = __builtin_amdgcn_mfma_f32_16x16x32_bf16(
                            ap, bv[kch][c], o[qf][c], 0, 0, 0);
            }
        }
    }

    const int b = bh / NH;
    const int h = bh - b * NH;
    #pragma unroll
    for (int qf = 0; qf < 2; qf++) {
        float l = l_lane[qf];
        l += __shfl_xor(l, 16, 64);
        l += __shfl_xor(l, 32, 64);
        #pragma unroll
        for (int r = 0; r < 4; r++) {
            float inv = 1.0f / __shfl(l, quad * 4 + r, 64);
            int tok = q0 + qf * 16 + quad * 4 + r;
            size_t off = (size_t)(b * SEQ + tok) * DIM + h * HD;
            #pragma unroll
            for (int c = 0; c < 4; c++)
                Ob[off + c * 16 + ln] = f2bf(o[qf][c][r] * inv);
        }
    }
}

// ---------------------------------------------------------------------------
// GEMM2: out = attn @ w_proj + b_proj, fp32 out
__global__ __launch_bounds__(256) void gemm_proj_k(
        const short* __restrict__ A, const short* __restrict__ WT,
        const float* __restrict__ bias, float* __restrict__ Out) {
    __shared__ short aL[2 * 128 * 64];
    __shared__ short bL[2 * 128 * 64];
    const int tid  = threadIdx.x;
    const int lane = tid & 63;
    const int ln   = lane & 15;
    const int quad = lane >> 4;
    const int wid  = tid >> 6;
    int xt, yt;
    xcd_map(blockIdx.x, DIM / 128, xt, yt);
    const int m0 = yt * 128;
    const int n0 = xt * 128;
    const int wm = (wid >> 1) * 64;
    const int wn = (wid & 1) * 64;

    const f32x4 vzero = {0.f, 0.f, 0.f, 0.f};
    f32x4 acc[4][4];
    #pragma unroll
    for (int i = 0; i < 4; i++)
        #pragma unroll
        for (int j = 0; j < 4; j++) acc[i][j] = vzero;

    gemm_core_128(A, WT, m0, n0, tid, aL, bL, acc);

    #pragma unroll
    for (int ni = 0; ni < 4; ni++) {
        int n = n0 + wn + ni * 16 + ln;
        float bi = bias[n];
        #pragma unroll
        for (int mi = 0; mi < 4; mi++) {
            #pragma unroll
            for (int r = 0; r < 4; r++) {
                int m = m0 + wm + mi * 16 + quad * 4 + r;
                Out[(size_t)m * DIM + n] = acc[mi][ni][r] + bi;
            }
        }
    }
}

// ---------------------------------------------------------------------------
extern "C" void kernel_launch(void* const* d_in, const int* in_sizes, int n_in,
                              void* d_out, int out_size, void* d_ws, size_t ws_size,
                              hipStream_t stream) {
    const float* x      = (const float*)d_in[0];
    const float* w_qkv  = (const float*)d_in[1];
    const float* w_proj = (const float*)d_in[2];
    const float* b_proj = (const float*)d_in[3];
    float* out = (float*)d_out;
    char* ws = (char*)d_ws;

    // ws layout (bytes), total 55,050,240 — xb aliases attn (xb dead before attn_k writes)
    short* wqkvT  = (short*)(ws);              //  3,538,944  [2304][768]
    short* wprojT = (short*)(ws +  3538944);   //  1,179,648  [768][768]
    short* qb     = (short*)(ws +  4718592);   // 12,582,912  [B,H,N,D] (pre-scaled)
    short* kb     = (short*)(ws + 17301504);   // 12,582,912  [B,H,N,D]
    short* vt     = (short*)(ws + 29884416);   // 12,582,912  [B,H,D,N]
    short* xb     = (short*)(ws + 42467328);   // 12,582,912  [B,N,768] (bf16 x, then attn out)
    short* attn   = xb;

    prep_k<<<dim3(6144 + (QKVN / 32) * (DIM / 32) + (DIM / 32) * (DIM / 32)), 256, 0, stream>>>(
            x, xb, w_qkv, wqkvT, w_proj, wprojT);
    gemm_qkv_k<<<dim3((QKVN / 128) * (NTOK / 128)), 256, 0, stream>>>(xb, wqkvT, qb, kb, vt);
    attn_k<<<dim3(BATCH * NH, SEQ / 128), 256, 0, stream>>>(qb, kb, vt, attn);
    gemm_proj_k<<<dim3((DIM / 128) * (NTOK / 128)), 256, 0, stream>>>(attn, wprojT, b_proj, out);
}